// Round 1
// baseline (95.264 us; speedup 1.0000x reference)
//
#include <hip/hip_runtime.h>

#define NB 8
#define NS 2048
#define ND 1024
#define NE 8

typedef unsigned short ushort_t;
typedef __attribute__((ext_vector_type(8))) short bf16x8;
typedef __attribute__((ext_vector_type(4))) float f32x4;

__device__ __forceinline__ unsigned short f2bf(float f) {
    union { float f; unsigned int u; } x; x.f = f;
    unsigned int u = x.u + 0x7fffu + ((x.u >> 16) & 1u);
    return (unsigned short)(u >> 16);
}

__device__ __forceinline__ void gload16(const void* g, void* l) {
    __builtin_amdgcn_global_load_lds(
        (const __attribute__((address_space(1))) unsigned int*)g,
        (__attribute__((address_space(3))) unsigned int*)l, 16, 0, 0);
}

// ---------------- routing: top-k gate coefs + expert counts ----------------
__global__ void routing_kernel(const float* __restrict__ scores,
                               const int* __restrict__ kp,
                               float* __restrict__ coef,
                               float* __restrict__ counts) {
    __shared__ int selS[NB][NE];
    int t = threadIdx.x;
    int k = *kp;
    if (t < NB) {
        float s[NE];
#pragma unroll
        for (int e = 0; e < NE; ++e) s[e] = scores[t * NE + e];
        bool sel[NE];
#pragma unroll
        for (int e = 0; e < NE; ++e) sel[e] = false;
        float sum = 0.f;
        for (int j = 0; j < k; ++j) {
            int best = 0; float bv = -3.4e38f;
#pragma unroll
            for (int e = 0; e < NE; ++e)
                if (!sel[e] && s[e] > bv) { bv = s[e]; best = e; }
            sel[best] = true; sum += bv;
        }
        float scale = 1.f / (sum + 1e-8f);
#pragma unroll
        for (int e = 0; e < NE; ++e) {
            coef[t * NE + e] = sel[e] ? scale * s[e] : 0.f;
            selS[t][e] = sel[e] ? 1 : 0;
        }
    }
    __syncthreads();
    if (t < NE) {
        int c = 0;
#pragma unroll
        for (int b = 0; b < NB; ++b) c += selS[b][t];
        counts[t] = (float)c;   // output 1: mask.sum(axis=0), written as float
    }
}

// ---------------- combined bias: bc[b][f] = sum_e coef*b_e[f] ----------------
__global__ void bias_kernel(const float* __restrict__ eb,
                            const float* __restrict__ coef,
                            float* __restrict__ bias) {
    int b = blockIdx.y;
    int f = blockIdx.x * 256 + threadIdx.x;
    float acc = 0.f;
#pragma unroll
    for (int e = 0; e < NE; ++e) {
        float c = coef[b * NE + e];
        if (c != 0.f) acc += c * eb[e * ND + f];
    }
    bias[b * ND + f] = acc;
}

// ---- combined weights, TRANSPOSED to [b][f][d] bf16 (so GEMM B-frags are K-contiguous) ----
__global__ void combine_kernel(const float* __restrict__ W,
                               const float* __restrict__ coef,
                               ushort_t* __restrict__ wct) {
    __shared__ float tile[64][65];   // +1 pad: conflict-free transposed reads
    int b = blockIdx.z;
    int d0 = blockIdx.y * 64, f0 = blockIdx.x * 64;
    int t = threadIdx.x;
    int lr = t >> 4;          // 0..15
    int lc = (t & 15) * 4;    // 0..60
    float4 acc[4];
#pragma unroll
    for (int it = 0; it < 4; ++it) acc[it] = make_float4(0.f, 0.f, 0.f, 0.f);
#pragma unroll
    for (int e = 0; e < NE; ++e) {
        float c = coef[b * NE + e];
        if (c != 0.f) {
            const float* We = W + ((size_t)e * ND * ND);
#pragma unroll
            for (int it = 0; it < 4; ++it) {
                int d = d0 + lr + it * 16;
                float4 v = *(const float4*)(We + (size_t)d * ND + f0 + lc);
                acc[it].x += c * v.x; acc[it].y += c * v.y;
                acc[it].z += c * v.z; acc[it].w += c * v.w;
            }
        }
    }
#pragma unroll
    for (int it = 0; it < 4; ++it) {
        int r = lr + it * 16;
        tile[r][lc + 0] = acc[it].x; tile[r][lc + 1] = acc[it].y;
        tile[r][lc + 2] = acc[it].z; tile[r][lc + 3] = acc[it].w;
    }
    __syncthreads();
    int dl = t & 63;          // d within tile
    int frow = t >> 6;        // 0..3
    ushort_t* dst = wct + (size_t)b * ND * ND + (size_t)f0 * ND + d0 + dl;
#pragma unroll
    for (int it = 0; it < 16; ++it) {
        int f = frow + it * 4;
        dst[(size_t)f * ND] = f2bf(tile[dl][f]);
    }
}

// ---------------- x fp32 -> bf16, vectorized ----------------
__global__ void convert_kernel(const float* __restrict__ x, ushort_t* __restrict__ xb) {
    int i = blockIdx.x * 256 + threadIdx.x;   // each thread: 8 elements
    const float4* p = (const float4*)x + 2 * (size_t)i;
    float4 a = p[0], b = p[1];
    uint4 o;
    o.x = (unsigned)f2bf(a.x) | ((unsigned)f2bf(a.y) << 16);
    o.y = (unsigned)f2bf(a.z) | ((unsigned)f2bf(a.w) << 16);
    o.z = (unsigned)f2bf(b.x) | ((unsigned)f2bf(b.y) << 16);
    o.w = (unsigned)f2bf(b.z) | ((unsigned)f2bf(b.w) << 16);
    ((uint4*)xb)[i] = o;
}

// ---------------- batched bf16 GEMM: out[b] = x[b] @ Wc[b] + bias[b] ----------------
// 128x128 tile, BK=32, 4 waves (2x2 of 64x64), 16x16x32 MFMA, global_load_lds(16)
__global__ __launch_bounds__(256) void gemm_kernel(const ushort_t* __restrict__ xb,
                                                   const ushort_t* __restrict__ wct,
                                                   const float* __restrict__ bias,
                                                   float* __restrict__ out) {
    __shared__ ushort_t lA[128 * 32];
    __shared__ ushort_t lB[128 * 32];
    int b = blockIdx.z;
    int m0 = blockIdx.y * 128, n0 = blockIdx.x * 128;
    const ushort_t* A  = xb  + ((size_t)b * NS * ND);
    const ushort_t* Bt = wct + ((size_t)b * ND * ND);
    int t = threadIdx.x, lane = t & 63, wave = t >> 6;
    int wr = wave >> 1, wc = wave & 1;

    // staging: thread t covers LDS bytes [t*16, t*16+16) (+4KB for second half)
    int srow = t >> 2;          // 0..63
    int scol = (t & 3) * 8;     // 0..24 (bf16 elements)
    const ushort_t* gA0 = A  + (size_t)(m0 + srow) * ND + scol;
    const ushort_t* gA1 = A  + (size_t)(m0 + 64 + srow) * ND + scol;
    const ushort_t* gB0 = Bt + (size_t)(n0 + srow) * ND + scol;
    const ushort_t* gB1 = Bt + (size_t)(n0 + 64 + srow) * ND + scol;
    ushort_t* lA0 = lA + wave * 512;          // wave-uniform base; HW adds lane*16B
    ushort_t* lA1 = lA + 2048 + wave * 512;
    ushort_t* lB0 = lB + wave * 512;
    ushort_t* lB1 = lB + 2048 + wave * 512;

    int fr = lane & 15, fq = lane >> 4;
    const ushort_t* pA = lA + (wr * 64 + fr) * 32 + fq * 8;
    const ushort_t* pB = lB + (wc * 64 + fr) * 32 + fq * 8;

    f32x4 acc[4][4];
#pragma unroll
    for (int i = 0; i < 4; ++i)
#pragma unroll
        for (int j = 0; j < 4; ++j) acc[i][j] = (f32x4){0.f, 0.f, 0.f, 0.f};

    for (int kt = 0; kt < ND / 32; ++kt) {
        gload16(gA0, lA0); gload16(gA1, lA1);
        gload16(gB0, lB0); gload16(gB1, lB1);
        gA0 += 32; gA1 += 32; gB0 += 32; gB1 += 32;
        __syncthreads();
        bf16x8 af[4], bfr[4];
#pragma unroll
        for (int mi = 0; mi < 4; ++mi) af[mi]  = *(const bf16x8*)(pA + mi * 512);
#pragma unroll
        for (int nj = 0; nj < 4; ++nj) bfr[nj] = *(const bf16x8*)(pB + nj * 512);
#pragma unroll
        for (int mi = 0; mi < 4; ++mi)
#pragma unroll
            for (int nj = 0; nj < 4; ++nj)
                acc[mi][nj] = __builtin_amdgcn_mfma_f32_16x16x32_bf16(
                    af[mi], bfr[nj], acc[mi][nj], 0, 0, 0);
        __syncthreads();
    }

    const float* bs = bias + b * ND;
    float* O = out + ((size_t)b * NS * ND);
#pragma unroll
    for (int mi = 0; mi < 4; ++mi) {
#pragma unroll
        for (int nj = 0; nj < 4; ++nj) {
            int col = n0 + wc * 64 + nj * 16 + fr;
            int row = m0 + wr * 64 + mi * 16 + fq * 4;
            float bv = bs[col];
            f32x4 v = acc[mi][nj];
#pragma unroll
            for (int r = 0; r < 4; ++r)
                O[(size_t)(row + r) * ND + col] = v[r] + bv;
        }
    }
}

extern "C" void kernel_launch(void* const* d_in, const int* in_sizes, int n_in,
                              void* d_out, int out_size, void* d_ws, size_t ws_size,
                              hipStream_t stream) {
    const float* x      = (const float*)d_in[0];
    const float* scores = (const float*)d_in[1];
    const float* Wx     = (const float*)d_in[2];
    const float* eb     = (const float*)d_in[3];
    const int*   kp     = (const int*)d_in[4];
    float* out = (float*)d_out;
    char* ws = (char*)d_ws;

    float*    coef  = (float*)(ws);                                    // 256 B
    float*    bias  = (float*)(ws + 1024);                             // 32 KB
    ushort_t* xbuf  = (ushort_t*)(ws + 65536);                         // 32 MB
    ushort_t* wct   = (ushort_t*)(ws + 65536 + (size_t)NB * NS * ND * 2); // 16 MB
    float*    counts = out + (size_t)NB * NS * ND;                     // output 1 tail

    routing_kernel<<<1, 64, 0, stream>>>(scores, kp, coef, counts);
    bias_kernel<<<dim3(ND / 256, NB), 256, 0, stream>>>(eb, coef, bias);
    combine_kernel<<<dim3(ND / 64, ND / 64, NB), 256, 0, stream>>>(Wx, coef, wct);
    convert_kernel<<<dim3(NB * NS * ND / 8 / 256), 256, 0, stream>>>(x, xbuf);
    gemm_kernel<<<dim3(ND / 128, NS / 128, NB), 256, 0, stream>>>(xbuf, wct, bias, out);
}

// Round 2
// 78.987 us; speedup vs baseline: 1.2061x; 1.2061x over previous
//
#include <hip/hip_runtime.h>

#define NB 8
#define NS 2048
#define ND 1024
#define NE 8

typedef unsigned short ushort_t;
typedef __attribute__((ext_vector_type(8))) short bf16x8;
typedef __attribute__((ext_vector_type(4))) float f32x4;

__device__ __forceinline__ unsigned short f2bf(float f) {
    union { float f; unsigned int u; } x; x.f = f;
    unsigned int u = x.u + 0x7fffu + ((x.u >> 16) & 1u);
    return (unsigned short)(u >> 16);
}

__device__ __forceinline__ void gload16(const void* g, void* l) {
    __builtin_amdgcn_global_load_lds(
        (const __attribute__((address_space(1))) unsigned int*)g,
        (__attribute__((address_space(3))) unsigned int*)l, 16, 0, 0);
}

// ---------------- routing: top-k gate coefs + expert counts ----------------
__global__ void routing_kernel(const float* __restrict__ scores,
                               const int* __restrict__ kp,
                               float* __restrict__ coef,
                               float* __restrict__ counts) {
    __shared__ int selS[NB][NE];
    int t = threadIdx.x;
    int k = *kp;
    if (t < NB) {
        float s[NE];
#pragma unroll
        for (int e = 0; e < NE; ++e) s[e] = scores[t * NE + e];
        bool sel[NE];
#pragma unroll
        for (int e = 0; e < NE; ++e) sel[e] = false;
        float sum = 0.f;
        for (int j = 0; j < k; ++j) {
            int best = 0; float bv = -3.4e38f;
#pragma unroll
            for (int e = 0; e < NE; ++e)
                if (!sel[e] && s[e] > bv) { bv = s[e]; best = e; }
            sel[best] = true; sum += bv;
        }
        float scale = 1.f / (sum + 1e-8f);
#pragma unroll
        for (int e = 0; e < NE; ++e) {
            coef[t * NE + e] = sel[e] ? scale * s[e] : 0.f;
            selS[t][e] = sel[e] ? 1 : 0;
        }
    }
    __syncthreads();
    if (t < NE) {
        int c = 0;
#pragma unroll
        for (int b = 0; b < NB; ++b) c += selS[b][t];
        counts[t] = (float)c;
    }
}

// ---------------- combined bias ----------------
__global__ void bias_kernel(const float* __restrict__ eb,
                            const float* __restrict__ coef,
                            float* __restrict__ bias) {
    int b = blockIdx.y;
    int f = blockIdx.x * 256 + threadIdx.x;
    float acc = 0.f;
#pragma unroll
    for (int e = 0; e < NE; ++e) {
        float c = coef[b * NE + e];
        if (c != 0.f) acc += c * eb[e * ND + f];
    }
    bias[b * ND + f] = acc;
}

// ---- combined weights, TRANSPOSED to [b][f][d] bf16 ----
__global__ void combine_kernel(const float* __restrict__ W,
                               const float* __restrict__ coef,
                               ushort_t* __restrict__ wct) {
    __shared__ float tile[64][65];
    int b = blockIdx.z;
    int d0 = blockIdx.y * 64, f0 = blockIdx.x * 64;
    int t = threadIdx.x;
    int lr = t >> 4;
    int lc = (t & 15) * 4;
    float4 acc[4];
#pragma unroll
    for (int it = 0; it < 4; ++it) acc[it] = make_float4(0.f, 0.f, 0.f, 0.f);
#pragma unroll
    for (int e = 0; e < NE; ++e) {
        float c = coef[b * NE + e];
        if (c != 0.f) {
            const float* We = W + ((size_t)e * ND * ND);
#pragma unroll
            for (int it = 0; it < 4; ++it) {
                int d = d0 + lr + it * 16;
                float4 v = *(const float4*)(We + (size_t)d * ND + f0 + lc);
                acc[it].x += c * v.x; acc[it].y += c * v.y;
                acc[it].z += c * v.z; acc[it].w += c * v.w;
            }
        }
    }
#pragma unroll
    for (int it = 0; it < 4; ++it) {
        int r = lr + it * 16;
        tile[r][lc + 0] = acc[it].x; tile[r][lc + 1] = acc[it].y;
        tile[r][lc + 2] = acc[it].z; tile[r][lc + 3] = acc[it].w;
    }
    __syncthreads();
    int dl = t & 63;
    int frow = t >> 6;
    ushort_t* dst = wct + (size_t)b * ND * ND + (size_t)f0 * ND + d0 + dl;
#pragma unroll
    for (int it = 0; it < 16; ++it) {
        int f = frow + it * 4;
        dst[(size_t)f * ND] = f2bf(tile[dl][f]);
    }
}

// ---------------- x fp32 -> bf16 ----------------
__global__ void convert_kernel(const float* __restrict__ x, ushort_t* __restrict__ xb) {
    int i = blockIdx.x * 256 + threadIdx.x;
    const float4* p = (const float4*)x + 2 * (size_t)i;
    float4 a = p[0], b = p[1];
    uint4 o;
    o.x = (unsigned)f2bf(a.x) | ((unsigned)f2bf(a.y) << 16);
    o.y = (unsigned)f2bf(a.z) | ((unsigned)f2bf(a.w) << 16);
    o.z = (unsigned)f2bf(b.x) | ((unsigned)f2bf(b.y) << 16);
    o.w = (unsigned)f2bf(b.z) | ((unsigned)f2bf(b.w) << 16);
    ((uint4*)xb)[i] = o;
}

// ============ 256x256 8-wave 4-phase GEMM, BK=64, swizzled LDS ============
// out[b] = x[b] @ WcT[b]^T + bias[b]; A=[2048][1024] bf16, Bt=[1024][1024] bf16
__global__ __launch_bounds__(512, 2) void gemm_kernel(const ushort_t* __restrict__ xb,
                                                      const ushort_t* __restrict__ wct,
                                                      const float* __restrict__ bias,
                                                      float* __restrict__ out) {
    __shared__ ushort_t ldsA[2][256 * 64];   // 64 KiB
    __shared__ ushort_t ldsB[2][256 * 64];   // 64 KiB

    int bid = blockIdx.x;
    int b = bid & 7;                 // batch -> XCD (round-robin % 8)
    int tile = bid >> 3;
    int m0 = (tile >> 2) * 256;
    int n0 = (tile & 3) * 256;
    const ushort_t* A  = xb  + ((size_t)b * NS * ND) + (size_t)m0 * ND;
    const ushort_t* Bt = wct + ((size_t)b * ND * ND) + (size_t)n0 * ND;

    int t = threadIdx.x, lane = t & 63, wave = t >> 6;
    int wm = wave >> 2, wn = wave & 3;          // 2 x 4 wave grid
    int fr = lane & 15, fq = lane >> 4;

    // ---- staging source (pre-swizzled: slot ^= row&7; LDS dest stays linear) ----
    int srow = lane >> 3;                       // 0..7
    int sslot = (lane & 7) ^ srow;              // involution
    const ushort_t* gA[4];
    const ushort_t* gB[4];
#pragma unroll
    for (int i = 0; i < 4; ++i) {
        int r = (i * 8 + wave) * 8 + srow;      // 0..255
        gA[i] = A  + (size_t)r * ND + sslot * 8;
        gB[i] = Bt + (size_t)r * ND + sslot * 8;
    }

    // ---- per-lane LDS fragment byte offsets (kk=0); kk=1 -> offset ^ 64 ----
    int sA = fq ^ (fr & 7);
    int aoff[8], boff[4];
#pragma unroll
    for (int mi = 0; mi < 8; ++mi) aoff[mi] = (wm * 128 + mi * 16 + fr) * 128 + sA * 16;
#pragma unroll
    for (int nj = 0; nj < 4; ++nj) boff[nj] = (wn * 64 + nj * 16 + fr) * 128 + sA * 16;

    f32x4 acc[8][4];
#pragma unroll
    for (int i = 0; i < 8; ++i)
#pragma unroll
        for (int j = 0; j < 4; ++j) acc[i][j] = (f32x4){0.f, 0.f, 0.f, 0.f};

    // ---- prologue: stage K-tile 0 into buf 0 ----
#pragma unroll
    for (int i = 0; i < 4; ++i) {
        gload16(gA[i], (char*)&ldsA[0][0] + (i * 8 + wave) * 1024);
        gload16(gB[i], (char*)&ldsB[0][0] + (i * 8 + wave) * 1024);
        gA[i] += 64; gB[i] += 64;
    }
    asm volatile("s_waitcnt vmcnt(0)" ::: "memory");
    __builtin_amdgcn_s_barrier();

    const int NT = ND / 64;   // 16 K-tiles
    for (int kt = 0; kt < NT; ++kt) {
        int cb = kt & 1;
        bool pre = (kt + 1 < NT);
        const char* lA = (const char*)&ldsA[cb][0];
        const char* lB = (const char*)&ldsB[cb][0];
        char* dA = (char*)&ldsA[cb ^ 1][0];
        char* dB = (char*)&ldsB[cb ^ 1][0];

        bf16x8 af[4], bfr[4];

        // ---- phase 0: kk=0, mi 0..3 (read B kk0 + A kk0 lo); stage A(t+1) ----
#pragma unroll
        for (int nj = 0; nj < 4; ++nj) bfr[nj] = *(const bf16x8*)(lB + boff[nj]);
#pragma unroll
        for (int mi = 0; mi < 4; ++mi) af[mi] = *(const bf16x8*)(lA + aoff[mi]);
        if (pre) {
#pragma unroll
            for (int i = 0; i < 4; ++i) {
                gload16(gA[i], dA + (i * 8 + wave) * 1024);
                gA[i] += 64;
            }
        }
        __builtin_amdgcn_sched_barrier(0);
        __builtin_amdgcn_s_barrier();
        asm volatile("s_waitcnt lgkmcnt(0)" ::: "memory");
        __builtin_amdgcn_sched_barrier(0);
        __builtin_amdgcn_s_setprio(1);
#pragma unroll
        for (int mi = 0; mi < 4; ++mi)
#pragma unroll
            for (int nj = 0; nj < 4; ++nj)
                acc[mi][nj] = __builtin_amdgcn_mfma_f32_16x16x32_bf16(af[mi], bfr[nj], acc[mi][nj], 0, 0, 0);
        __builtin_amdgcn_s_setprio(0);
        __builtin_amdgcn_s_barrier();

        // ---- phase 1: kk=0, mi 4..7 (B reused); stage B(t+1) ----
#pragma unroll
        for (int mi = 0; mi < 4; ++mi) af[mi] = *(const bf16x8*)(lA + aoff[mi + 4]);
        if (pre) {
#pragma unroll
            for (int i = 0; i < 4; ++i) {
                gload16(gB[i], dB + (i * 8 + wave) * 1024);
                gB[i] += 64;
            }
        }
        __builtin_amdgcn_sched_barrier(0);
        __builtin_amdgcn_s_barrier();
        asm volatile("s_waitcnt lgkmcnt(0)" ::: "memory");
        __builtin_amdgcn_sched_barrier(0);
        __builtin_amdgcn_s_setprio(1);
#pragma unroll
        for (int mi = 0; mi < 4; ++mi)
#pragma unroll
            for (int nj = 0; nj < 4; ++nj)
                acc[mi + 4][nj] = __builtin_amdgcn_mfma_f32_16x16x32_bf16(af[mi], bfr[nj], acc[mi + 4][nj], 0, 0, 0);
        __builtin_amdgcn_s_setprio(0);
        __builtin_amdgcn_s_barrier();

        // ---- phase 2: kk=1, mi 0..3 ----
#pragma unroll
        for (int nj = 0; nj < 4; ++nj) bfr[nj] = *(const bf16x8*)(lB + (boff[nj] ^ 64));
#pragma unroll
        for (int mi = 0; mi < 4; ++mi) af[mi] = *(const bf16x8*)(lA + (aoff[mi] ^ 64));
        __builtin_amdgcn_sched_barrier(0);
        __builtin_amdgcn_s_barrier();
        asm volatile("s_waitcnt lgkmcnt(0)" ::: "memory");
        __builtin_amdgcn_sched_barrier(0);
        __builtin_amdgcn_s_setprio(1);
#pragma unroll
        for (int mi = 0; mi < 4; ++mi)
#pragma unroll
            for (int nj = 0; nj < 4; ++nj)
                acc[mi][nj] = __builtin_amdgcn_mfma_f32_16x16x32_bf16(af[mi], bfr[nj], acc[mi][nj], 0, 0, 0);
        __builtin_amdgcn_s_setprio(0);
        __builtin_amdgcn_s_barrier();

        // ---- phase 3: kk=1, mi 4..7; then single per-tile vmem drain ----
#pragma unroll
        for (int mi = 0; mi < 4; ++mi) af[mi] = *(const bf16x8*)(lA + (aoff[mi + 4] ^ 64));
        __builtin_amdgcn_sched_barrier(0);
        __builtin_amdgcn_s_barrier();
        asm volatile("s_waitcnt lgkmcnt(0)" ::: "memory");
        __builtin_amdgcn_sched_barrier(0);
        __builtin_amdgcn_s_setprio(1);
#pragma unroll
        for (int mi = 0; mi < 4; ++mi)
#pragma unroll
            for (int nj = 0; nj < 4; ++nj)
                acc[mi + 4][nj] = __builtin_amdgcn_mfma_f32_16x16x32_bf16(af[mi], bfr[nj], acc[mi + 4][nj], 0, 0, 0);
        __builtin_amdgcn_s_setprio(0);
        asm volatile("s_waitcnt vmcnt(0)" ::: "memory");
        __builtin_amdgcn_s_barrier();
    }

    // ---- epilogue: bias + fp32 store ----
    const float* bs = bias + b * ND;
    float* O = out + ((size_t)b * NS * ND);
#pragma unroll
    for (int mi = 0; mi < 8; ++mi) {
        int row = m0 + wm * 128 + mi * 16 + fq * 4;
#pragma unroll
        for (int nj = 0; nj < 4; ++nj) {
            int col = n0 + wn * 64 + nj * 16 + fr;
            float bv = bs[col];
            f32x4 v = acc[mi][nj];
#pragma unroll
            for (int r = 0; r < 4; ++r)
                O[(size_t)(row + r) * ND + col] = v[r] + bv;
        }
    }
}

extern "C" void kernel_launch(void* const* d_in, const int* in_sizes, int n_in,
                              void* d_out, int out_size, void* d_ws, size_t ws_size,
                              hipStream_t stream) {
    const float* x      = (const float*)d_in[0];
    const float* scores = (const float*)d_in[1];
    const float* Wx     = (const float*)d_in[2];
    const float* eb     = (const float*)d_in[3];
    const int*   kp     = (const int*)d_in[4];
    float* out = (float*)d_out;
    char* ws = (char*)d_ws;

    float*    coef  = (float*)(ws);
    float*    bias  = (float*)(ws + 1024);
    ushort_t* xbuf  = (ushort_t*)(ws + 65536);
    ushort_t* wct   = (ushort_t*)(ws + 65536 + (size_t)NB * NS * ND * 2);
    float*    counts = out + (size_t)NB * NS * ND;

    routing_kernel<<<1, 64, 0, stream>>>(scores, kp, coef, counts);
    bias_kernel<<<dim3(ND / 256, NB), 256, 0, stream>>>(eb, coef, bias);
    combine_kernel<<<dim3(ND / 64, ND / 64, NB), 256, 0, stream>>>(Wx, coef, wct);
    convert_kernel<<<dim3(NB * NS * ND / 8 / 256), 256, 0, stream>>>(x, xbuf);
    gemm_kernel<<<256, 512, 0, stream>>>(xbuf, wct, bias, out);
}

// Round 3
// 78.554 us; speedup vs baseline: 1.2127x; 1.0055x over previous
//
#include <hip/hip_runtime.h>

#define NB 8
#define NS 2048
#define ND 1024
#define NE 8

typedef unsigned short ushort_t;
typedef __attribute__((ext_vector_type(8))) short bf16x8;
typedef __attribute__((ext_vector_type(4))) float f32x4;

__device__ __forceinline__ unsigned short f2bf(float f) {
    union { float f; unsigned int u; } x; x.f = f;
    unsigned int u = x.u + 0x7fffu + ((x.u >> 16) & 1u);
    return (unsigned short)(u >> 16);
}

__device__ __forceinline__ void gload16(const void* g, void* l) {
    __builtin_amdgcn_global_load_lds(
        (const __attribute__((address_space(1))) unsigned int*)g,
        (__attribute__((address_space(3))) unsigned int*)l, 16, 0, 0);
}

// ---------------- routing: top-k gate coefs + expert counts ----------------
__global__ void routing_kernel(const float* __restrict__ scores,
                               const int* __restrict__ kp,
                               float* __restrict__ coef,
                               float* __restrict__ counts) {
    __shared__ int selS[NB][NE];
    int t = threadIdx.x;
    int k = *kp;
    if (t < NB) {
        float s[NE];
#pragma unroll
        for (int e = 0; e < NE; ++e) s[e] = scores[t * NE + e];
        bool sel[NE];
#pragma unroll
        for (int e = 0; e < NE; ++e) sel[e] = false;
        float sum = 0.f;
        for (int j = 0; j < k; ++j) {
            int best = 0; float bv = -3.4e38f;
#pragma unroll
            for (int e = 0; e < NE; ++e)
                if (!sel[e] && s[e] > bv) { bv = s[e]; best = e; }
            sel[best] = true; sum += bv;
        }
        float scale = 1.f / (sum + 1e-8f);
#pragma unroll
        for (int e = 0; e < NE; ++e) {
            coef[t * NE + e] = sel[e] ? scale * s[e] : 0.f;
            selS[t][e] = sel[e] ? 1 : 0;
        }
    }
    __syncthreads();
    if (t < NE) {
        int c = 0;
#pragma unroll
        for (int b = 0; b < NB; ++b) c += selS[b][t];
        counts[t] = (float)c;
    }
}

// ---------------- combined bias ----------------
__global__ void bias_kernel(const float* __restrict__ eb,
                            const float* __restrict__ coef,
                            float* __restrict__ bias) {
    int b = blockIdx.y;
    int f = blockIdx.x * 256 + threadIdx.x;
    float acc = 0.f;
#pragma unroll
    for (int e = 0; e < NE; ++e) {
        float c = coef[b * NE + e];
        if (c != 0.f) acc += c * eb[e * ND + f];
    }
    bias[b * ND + f] = acc;
}

// ---- combined weights, TRANSPOSED to [b][f][d] bf16 ----
__global__ void combine_kernel(const float* __restrict__ W,
                               const float* __restrict__ coef,
                               ushort_t* __restrict__ wct) {
    __shared__ float tile[64][65];
    int b = blockIdx.z;
    int d0 = blockIdx.y * 64, f0 = blockIdx.x * 64;
    int t = threadIdx.x;
    int lr = t >> 4;
    int lc = (t & 15) * 4;
    float4 acc[4];
#pragma unroll
    for (int it = 0; it < 4; ++it) acc[it] = make_float4(0.f, 0.f, 0.f, 0.f);
#pragma unroll
    for (int e = 0; e < NE; ++e) {
        float c = coef[b * NE + e];
        if (c != 0.f) {
            const float* We = W + ((size_t)e * ND * ND);
#pragma unroll
            for (int it = 0; it < 4; ++it) {
                int d = d0 + lr + it * 16;
                float4 v = *(const float4*)(We + (size_t)d * ND + f0 + lc);
                acc[it].x += c * v.x; acc[it].y += c * v.y;
                acc[it].z += c * v.z; acc[it].w += c * v.w;
            }
        }
    }
#pragma unroll
    for (int it = 0; it < 4; ++it) {
        int r = lr + it * 16;
        tile[r][lc + 0] = acc[it].x; tile[r][lc + 1] = acc[it].y;
        tile[r][lc + 2] = acc[it].z; tile[r][lc + 3] = acc[it].w;
    }
    __syncthreads();
    int dl = t & 63;
    int frow = t >> 6;
    ushort_t* dst = wct + (size_t)b * ND * ND + (size_t)f0 * ND + d0 + dl;
#pragma unroll
    for (int it = 0; it < 16; ++it) {
        int f = frow + it * 4;
        dst[(size_t)f * ND] = f2bf(tile[dl][f]);
    }
}

// ---------------- x fp32 -> bf16 ----------------
__global__ void convert_kernel(const float* __restrict__ x, ushort_t* __restrict__ xb) {
    int i = blockIdx.x * 256 + threadIdx.x;
    const float4* p = (const float4*)x + 2 * (size_t)i;
    float4 a = p[0], b = p[1];
    uint4 o;
    o.x = (unsigned)f2bf(a.x) | ((unsigned)f2bf(a.y) << 16);
    o.y = (unsigned)f2bf(a.z) | ((unsigned)f2bf(a.w) << 16);
    o.z = (unsigned)f2bf(b.x) | ((unsigned)f2bf(b.y) << 16);
    o.w = (unsigned)f2bf(b.z) | ((unsigned)f2bf(b.w) << 16);
    ((uint4*)xb)[i] = o;
}

// ====== 256x256 8-wave GEMM, BK=32, 4-buffer LDS, 3-deep counted vmcnt ======
// out[b] = x[b] @ WcT[b]^T + bias[b]; A=[2048][1024] bf16, Bt=[1024][1024] bf16
__global__ __launch_bounds__(512, 2) void gemm_kernel(const ushort_t* __restrict__ xb,
                                                      const ushort_t* __restrict__ wct,
                                                      const float* __restrict__ bias,
                                                      float* __restrict__ out) {
    __shared__ ushort_t ldsA[4][256 * 32];   // 4 x 16 KiB
    __shared__ ushort_t ldsB[4][256 * 32];   // 4 x 16 KiB

    int bid = blockIdx.x;
    int b = bid & 7;                 // batch -> XCD (round-robin % 8)
    int tile = bid >> 3;
    int m0 = (tile >> 2) * 256;
    int n0 = (tile & 3) * 256;
    const ushort_t* A  = xb  + ((size_t)b * NS * ND) + (size_t)m0 * ND;
    const ushort_t* Bt = wct + ((size_t)b * ND * ND) + (size_t)n0 * ND;

    int t = threadIdx.x, lane = t & 63, wave = t >> 6;
    int wm = wave >> 2, wn = wave & 3;          // 2 x 4 wave grid
    int fr = lane & 15, fq = lane >> 4;

    // ---- staging source (pre-swizzled slot; LDS dest linear) ----
    // rows of 32 bf16 = 4 slots of 16B; slot ^= (row&3)^((row>>2)&3)
    int srow = t >> 2;                              // 0..127
    int fsrc = ((t >> 2) & 3) ^ ((t >> 4) & 3);
    int sslot = (t & 3) ^ fsrc;
    const ushort_t* gA[2];
    const ushort_t* gB[2];
#pragma unroll
    for (int i = 0; i < 2; ++i) {
        gA[i] = A  + (size_t)(i * 128 + srow) * ND + sslot * 8;
        gB[i] = Bt + (size_t)(i * 128 + srow) * ND + sslot * 8;
    }

    // ---- per-lane LDS fragment byte offsets ----
    int fswz = (fr & 3) ^ ((fr >> 2) & 3);
    int slotr = (fq ^ fswz) * 16;
    int aoff[8], boff[4];
#pragma unroll
    for (int mi = 0; mi < 8; ++mi) aoff[mi] = (wm * 128 + mi * 16 + fr) * 64 + slotr;
#pragma unroll
    for (int nj = 0; nj < 4; ++nj) boff[nj] = (wn * 64 + nj * 16 + fr) * 64 + slotr;

    f32x4 acc[8][4];
#pragma unroll
    for (int i = 0; i < 8; ++i)
#pragma unroll
        for (int j = 0; j < 4; ++j) acc[i][j] = (f32x4){0.f, 0.f, 0.f, 0.f};

    const int NT = ND / 32;   // 32 K-tiles

    // ---- prologue: stage K-tiles 0,1,2 into bufs 0,1,2 (A then B per tile) ----
#pragma unroll
    for (int T = 0; T < 3; ++T) {
#pragma unroll
        for (int i = 0; i < 2; ++i) {
            gload16(gA[i], (char*)&ldsA[T][0] + i * 8192 + wave * 1024);
            gA[i] += 32;
        }
#pragma unroll
        for (int i = 0; i < 2; ++i) {
            gload16(gB[i], (char*)&ldsB[T][0] + i * 8192 + wave * 1024);
            gB[i] += 32;
        }
    }
    asm volatile("s_waitcnt vmcnt(8)" ::: "memory");   // tile 0 landed
    __builtin_amdgcn_s_barrier();

    for (int kt = 0; kt < NT; ++kt) {
        int cur = kt & 3;
        const char* lA = (const char*)&ldsA[cur][0];
        const char* lB = (const char*)&ldsB[cur][0];
        bool pre = (kt + 3 < NT);
        int nb = (kt + 3) & 3;
        char* dA = (char*)&ldsA[nb][0];
        char* dB = (char*)&ldsB[nb][0];

        bf16x8 af[4], bfr[4];

        // ---- phase 0: mi 0..3 ; stage A(kt+3) ----
#pragma unroll
        for (int nj = 0; nj < 4; ++nj) bfr[nj] = *(const bf16x8*)(lB + boff[nj]);
#pragma unroll
        for (int mi = 0; mi < 4; ++mi) af[mi] = *(const bf16x8*)(lA + aoff[mi]);
        if (pre) {
#pragma unroll
            for (int i = 0; i < 2; ++i) {
                gload16(gA[i], dA + i * 8192 + wave * 1024);
                gA[i] += 32;
            }
        }
        __builtin_amdgcn_sched_barrier(0);
        __builtin_amdgcn_s_barrier();
        asm volatile("s_waitcnt lgkmcnt(0)" ::: "memory");
        __builtin_amdgcn_sched_barrier(0);
        __builtin_amdgcn_s_setprio(1);
#pragma unroll
        for (int mi = 0; mi < 4; ++mi)
#pragma unroll
            for (int nj = 0; nj < 4; ++nj)
                acc[mi][nj] = __builtin_amdgcn_mfma_f32_16x16x32_bf16(af[mi], bfr[nj], acc[mi][nj], 0, 0, 0);
        __builtin_amdgcn_s_setprio(0);
        __builtin_amdgcn_s_barrier();

        // ---- phase 1: mi 4..7 (B reused); stage B(kt+3); counted drain ----
#pragma unroll
        for (int mi = 0; mi < 4; ++mi) af[mi] = *(const bf16x8*)(lA + aoff[mi + 4]);
        if (pre) {
#pragma unroll
            for (int i = 0; i < 2; ++i) {
                gload16(gB[i], dB + i * 8192 + wave * 1024);
                gB[i] += 32;
            }
        }
        __builtin_amdgcn_sched_barrier(0);
        __builtin_amdgcn_s_barrier();
        asm volatile("s_waitcnt lgkmcnt(0)" ::: "memory");
        __builtin_amdgcn_sched_barrier(0);
        __builtin_amdgcn_s_setprio(1);
#pragma unroll
        for (int mi = 0; mi < 4; ++mi)
#pragma unroll
            for (int nj = 0; nj < 4; ++nj)
                acc[mi + 4][nj] = __builtin_amdgcn_mfma_f32_16x16x32_bf16(af[mi], bfr[nj], acc[mi + 4][nj], 0, 0, 0);
        __builtin_amdgcn_s_setprio(0);
        // wait only for the NEXT tile's 4 loads; keep up to 8 in flight
        if (kt < NT - 3) {
            asm volatile("s_waitcnt vmcnt(8)" ::: "memory");
        } else if (kt == NT - 3) {
            asm volatile("s_waitcnt vmcnt(4)" ::: "memory");
        } else if (kt == NT - 2) {
            asm volatile("s_waitcnt vmcnt(0)" ::: "memory");
        }
        __builtin_amdgcn_s_barrier();
    }

    // ---- epilogue: bias + fp32 store ----
    const float* bs = bias + b * ND;
    float* O = out + ((size_t)b * NS * ND);
#pragma unroll
    for (int mi = 0; mi < 8; ++mi) {
        int row = m0 + wm * 128 + mi * 16 + fq * 4;
#pragma unroll
        for (int nj = 0; nj < 4; ++nj) {
            int col = n0 + wn * 64 + nj * 16 + fr;
            float bv = bs[col];
            f32x4 v = acc[mi][nj];
#pragma unroll
            for (int r = 0; r < 4; ++r)
                O[(size_t)(row + r) * ND + col] = v[r] + bv;
        }
    }
}

extern "C" void kernel_launch(void* const* d_in, const int* in_sizes, int n_in,
                              void* d_out, int out_size, void* d_ws, size_t ws_size,
                              hipStream_t stream) {
    const float* x      = (const float*)d_in[0];
    const float* scores = (const float*)d_in[1];
    const float* Wx     = (const float*)d_in[2];
    const float* eb     = (const float*)d_in[3];
    const int*   kp     = (const int*)d_in[4];
    float* out = (float*)d_out;
    char* ws = (char*)d_ws;

    float*    coef  = (float*)(ws);
    float*    bias  = (float*)(ws + 1024);
    ushort_t* xbuf  = (ushort_t*)(ws + 65536);
    ushort_t* wct   = (ushort_t*)(ws + 65536 + (size_t)NB * NS * ND * 2);
    float*    counts = out + (size_t)NB * NS * ND;

    routing_kernel<<<1, 64, 0, stream>>>(scores, kp, coef, counts);
    bias_kernel<<<dim3(ND / 256, NB), 256, 0, stream>>>(eb, coef, bias);
    combine_kernel<<<dim3(ND / 64, ND / 64, NB), 256, 0, stream>>>(Wx, coef, wct);
    convert_kernel<<<dim3(NB * NS * ND / 8 / 256), 256, 0, stream>>>(x, xbuf);
    gemm_kernel<<<256, 512, 0, stream>>>(xbuf, wct, bias, out);
}

// Round 4
// 73.838 us; speedup vs baseline: 1.2902x; 1.0639x over previous
//
#include <hip/hip_runtime.h>

#define NB 8
#define NS 2048
#define ND 1024
#define NE 8

typedef unsigned short ushort_t;
typedef __attribute__((ext_vector_type(8))) short bf16x8;
typedef __attribute__((ext_vector_type(4))) float f32x4;

__device__ __forceinline__ unsigned short f2bf(float f) {
    union { float f; unsigned int u; } x; x.f = f;
    unsigned int u = x.u + 0x7fffu + ((x.u >> 16) & 1u);
    return (unsigned short)(u >> 16);
}

__device__ __forceinline__ void gload16(const void* g, void* l) {
    __builtin_amdgcn_global_load_lds(
        (const __attribute__((address_space(1))) unsigned int*)g,
        (__attribute__((address_space(3))) unsigned int*)l, 16, 0, 0);
}

// ---------------- routing: top-k gate coefs + expert counts ----------------
__global__ void routing_kernel(const float* __restrict__ scores,
                               const int* __restrict__ kp,
                               float* __restrict__ coef,
                               float* __restrict__ counts) {
    __shared__ int selS[NB][NE];
    int t = threadIdx.x;
    int k = *kp;
    if (t < NB) {
        float s[NE];
#pragma unroll
        for (int e = 0; e < NE; ++e) s[e] = scores[t * NE + e];
        bool sel[NE];
#pragma unroll
        for (int e = 0; e < NE; ++e) sel[e] = false;
        float sum = 0.f;
        for (int j = 0; j < k; ++j) {
            int best = 0; float bv = -3.4e38f;
#pragma unroll
            for (int e = 0; e < NE; ++e)
                if (!sel[e] && s[e] > bv) { bv = s[e]; best = e; }
            sel[best] = true; sum += bv;
        }
        float scale = 1.f / (sum + 1e-8f);
#pragma unroll
        for (int e = 0; e < NE; ++e) {
            coef[t * NE + e] = sel[e] ? scale * s[e] : 0.f;
            selS[t][e] = sel[e] ? 1 : 0;
        }
    }
    __syncthreads();
    if (t < NE) {
        int c = 0;
#pragma unroll
        for (int b = 0; b < NB; ++b) c += selS[b][t];
        counts[t] = (float)c;
    }
}

// ---------------- combined bias ----------------
__global__ void bias_kernel(const float* __restrict__ eb,
                            const float* __restrict__ coef,
                            float* __restrict__ bias) {
    int b = blockIdx.y;
    int f = blockIdx.x * 256 + threadIdx.x;
    float acc = 0.f;
#pragma unroll
    for (int e = 0; e < NE; ++e) {
        float c = coef[b * NE + e];
        if (c != 0.f) acc += c * eb[e * ND + f];
    }
    bias[b * ND + f] = acc;
}

// ---- combined weights, TRANSPOSED to [b][f][d] bf16 ----
__global__ void combine_kernel(const float* __restrict__ W,
                               const float* __restrict__ coef,
                               ushort_t* __restrict__ wct) {
    __shared__ float tile[64][65];
    int b = blockIdx.z;
    int d0 = blockIdx.y * 64, f0 = blockIdx.x * 64;
    int t = threadIdx.x;
    int lr = t >> 4;
    int lc = (t & 15) * 4;
    float4 acc[4];
#pragma unroll
    for (int it = 0; it < 4; ++it) acc[it] = make_float4(0.f, 0.f, 0.f, 0.f);
#pragma unroll
    for (int e = 0; e < NE; ++e) {
        float c = coef[b * NE + e];
        if (c != 0.f) {
            const float* We = W + ((size_t)e * ND * ND);
#pragma unroll
            for (int it = 0; it < 4; ++it) {
                int d = d0 + lr + it * 16;
                float4 v = *(const float4*)(We + (size_t)d * ND + f0 + lc);
                acc[it].x += c * v.x; acc[it].y += c * v.y;
                acc[it].z += c * v.z; acc[it].w += c * v.w;
            }
        }
    }
#pragma unroll
    for (int it = 0; it < 4; ++it) {
        int r = lr + it * 16;
        tile[r][lc + 0] = acc[it].x; tile[r][lc + 1] = acc[it].y;
        tile[r][lc + 2] = acc[it].z; tile[r][lc + 3] = acc[it].w;
    }
    __syncthreads();
    int dl = t & 63;
    int frow = t >> 6;
    ushort_t* dst = wct + (size_t)b * ND * ND + (size_t)f0 * ND + d0 + dl;
#pragma unroll
    for (int it = 0; it < 16; ++it) {
        int f = frow + it * 4;
        dst[(size_t)f * ND] = f2bf(tile[dl][f]);
    }
}

// ---------------- x fp32 -> bf16 ----------------
__global__ void convert_kernel(const float* __restrict__ x, ushort_t* __restrict__ xb) {
    int i = blockIdx.x * 256 + threadIdx.x;
    const float4* p = (const float4*)x + 2 * (size_t)i;
    float4 a = p[0], b = p[1];
    uint4 o;
    o.x = (unsigned)f2bf(a.x) | ((unsigned)f2bf(a.y) << 16);
    o.y = (unsigned)f2bf(a.z) | ((unsigned)f2bf(a.w) << 16);
    o.z = (unsigned)f2bf(b.x) | ((unsigned)f2bf(b.y) << 16);
    o.w = (unsigned)f2bf(b.z) | ((unsigned)f2bf(b.w) << 16);
    ((uint4*)xb)[i] = o;
}

// ====== 256x256 8-wave GEMM, BK=64, 2-buffer LDS, 1 barrier/K-tile ======
// In-tile register pipelining: counted lgkmcnt gates 4 x 16-MFMA quadrants.
__global__ __launch_bounds__(512, 2) void gemm_kernel(const ushort_t* __restrict__ xb,
                                                      const ushort_t* __restrict__ wct,
                                                      const float* __restrict__ bias,
                                                      float* __restrict__ out) {
    __shared__ ushort_t ldsA[2][256 * 64];   // 2 x 32 KiB
    __shared__ ushort_t ldsB[2][256 * 64];   // 2 x 32 KiB

    int bid = blockIdx.x;
    int b = bid & 7;                 // batch -> XCD (round-robin % 8)
    int tile = bid >> 3;
    int m0 = (tile >> 2) * 256;
    int n0 = (tile & 3) * 256;
    const ushort_t* A  = xb  + ((size_t)b * NS * ND) + (size_t)m0 * ND;
    const ushort_t* Bt = wct + ((size_t)b * ND * ND) + (size_t)n0 * ND;

    int t = threadIdx.x, lane = t & 63, wave = t >> 6;
    int wm = wave >> 2, wn = wave & 3;          // 2 x 4 wave grid
    int fr = lane & 15, fq = lane >> 4;

    // ---- staging source (pre-swizzled slot8 ^= row&7; LDS dest linear) ----
    int srow = lane >> 3;                       // 0..7
    int sslot = (lane & 7) ^ srow;
    const ushort_t* gA[4];
    const ushort_t* gB[4];
#pragma unroll
    for (int i = 0; i < 4; ++i) {
        int r = (i * 8 + wave) * 8 + srow;      // 0..255
        gA[i] = A  + (size_t)r * ND + sslot * 8;
        gB[i] = Bt + (size_t)r * ND + sslot * 8;
    }

    // ---- per-lane LDS fragment byte offsets (k0); k1 -> ^64 ----
    int slotr = (fq ^ (fr & 7)) * 16;
    int aoff[8], boff[4];
#pragma unroll
    for (int mi = 0; mi < 8; ++mi) aoff[mi] = (wm * 128 + mi * 16 + fr) * 128 + slotr;
#pragma unroll
    for (int nj = 0; nj < 4; ++nj) boff[nj] = (wn * 64 + nj * 16 + fr) * 128 + slotr;

    f32x4 acc[8][4];
#pragma unroll
    for (int i = 0; i < 8; ++i)
#pragma unroll
        for (int j = 0; j < 4; ++j) acc[i][j] = (f32x4){0.f, 0.f, 0.f, 0.f};

    const int NT = ND / 64;   // 16 K-tiles

    // ---- prologue: stage K-tile 0 into buf 0 ----
#pragma unroll
    for (int i = 0; i < 4; ++i) {
        gload16(gA[i], (char*)&ldsA[0][0] + (i * 8 + wave) * 1024);
        gA[i] += 64;
    }
#pragma unroll
    for (int i = 0; i < 4; ++i) {
        gload16(gB[i], (char*)&ldsB[0][0] + (i * 8 + wave) * 1024);
        gB[i] += 64;
    }
    asm volatile("s_waitcnt vmcnt(0)" ::: "memory");
    __builtin_amdgcn_s_barrier();

    for (int kt = 0; kt < NT; ++kt) {
        const char* lA = (const char*)&ldsA[kt & 1][0];
        const char* lB = (const char*)&ldsB[kt & 1][0];
        bool pre = (kt + 1 < NT);
        char* dA = (char*)&ldsA[(kt + 1) & 1][0];
        char* dB = (char*)&ldsB[(kt + 1) & 1][0];

        __builtin_amdgcn_sched_barrier(0);
        bf16x8 bf0[4], bf1[4], a0[4], a1[4], a2[4], a3[4];
        // issue: B k0(4), A g0(4), B k1(4), A g1(4)  -> 16 outstanding
#pragma unroll
        for (int nj = 0; nj < 4; ++nj) bf0[nj] = *(const bf16x8*)(lB + boff[nj]);
#pragma unroll
        for (int mi = 0; mi < 4; ++mi) a0[mi] = *(const bf16x8*)(lA + aoff[mi]);
#pragma unroll
        for (int nj = 0; nj < 4; ++nj) bf1[nj] = *(const bf16x8*)(lB + (boff[nj] ^ 64));
#pragma unroll
        for (int mi = 0; mi < 4; ++mi) a1[mi] = *(const bf16x8*)(lA + aoff[mi + 4]);
        // stage A(kt+1)
        if (pre) {
#pragma unroll
            for (int i = 0; i < 4; ++i) {
                gload16(gA[i], dA + (i * 8 + wave) * 1024);
                gA[i] += 64;
            }
        }
        __builtin_amdgcn_sched_barrier(0);
        asm volatile("s_waitcnt lgkmcnt(8)" ::: "memory");   // Bk0 + Ag0 landed
        __builtin_amdgcn_sched_barrier(0);
        __builtin_amdgcn_s_setprio(1);
#pragma unroll
        for (int mi = 0; mi < 4; ++mi)
#pragma unroll
            for (int nj = 0; nj < 4; ++nj)
                acc[mi][nj] = __builtin_amdgcn_mfma_f32_16x16x32_bf16(a0[mi], bf0[nj], acc[mi][nj], 0, 0, 0);
        __builtin_amdgcn_s_setprio(0);
        // issue A g2 (k1, m0-3); stage B(kt+1)
#pragma unroll
        for (int mi = 0; mi < 4; ++mi) a2[mi] = *(const bf16x8*)(lA + (aoff[mi] ^ 64));
        if (pre) {
#pragma unroll
            for (int i = 0; i < 4; ++i) {
                gload16(gB[i], dB + (i * 8 + wave) * 1024);
                gB[i] += 64;
            }
        }
        __builtin_amdgcn_sched_barrier(0);
        asm volatile("s_waitcnt lgkmcnt(4)" ::: "memory");   // Bk1 + Ag1 landed
        __builtin_amdgcn_sched_barrier(0);
        __builtin_amdgcn_s_setprio(1);
#pragma unroll
        for (int mi = 0; mi < 4; ++mi)
#pragma unroll
            for (int nj = 0; nj < 4; ++nj)
                acc[mi + 4][nj] = __builtin_amdgcn_mfma_f32_16x16x32_bf16(a1[mi], bf0[nj], acc[mi + 4][nj], 0, 0, 0);
        __builtin_amdgcn_s_setprio(0);
        // issue A g3 (k1, m4-7)
#pragma unroll
        for (int mi = 0; mi < 4; ++mi) a3[mi] = *(const bf16x8*)(lA + (aoff[mi + 4] ^ 64));
        __builtin_amdgcn_sched_barrier(0);
        asm volatile("s_waitcnt lgkmcnt(4)" ::: "memory");   // Ag2 landed
        __builtin_amdgcn_sched_barrier(0);
        __builtin_amdgcn_s_setprio(1);
#pragma unroll
        for (int mi = 0; mi < 4; ++mi)
#pragma unroll
            for (int nj = 0; nj < 4; ++nj)
                acc[mi][nj] = __builtin_amdgcn_mfma_f32_16x16x32_bf16(a2[mi], bf1[nj], acc[mi][nj], 0, 0, 0);
        __builtin_amdgcn_s_setprio(0);
        __builtin_amdgcn_sched_barrier(0);
        asm volatile("s_waitcnt lgkmcnt(0)" ::: "memory");   // Ag3 landed
        __builtin_amdgcn_sched_barrier(0);
        __builtin_amdgcn_s_setprio(1);
#pragma unroll
        for (int mi = 0; mi < 4; ++mi)
#pragma unroll
            for (int nj = 0; nj < 4; ++nj)
                acc[mi + 4][nj] = __builtin_amdgcn_mfma_f32_16x16x32_bf16(a3[mi], bf1[nj], acc[mi + 4][nj], 0, 0, 0);
        __builtin_amdgcn_s_setprio(0);
        __builtin_amdgcn_sched_barrier(0);
        if (pre) {
            asm volatile("s_waitcnt vmcnt(0)" ::: "memory");  // kt+1 fully staged (issued a full tile ago)
            __builtin_amdgcn_s_barrier();
        }
    }

    // ---- epilogue: bias + fp32 store ----
    const float* bs = bias + b * ND;
    float* O = out + ((size_t)b * NS * ND);
#pragma unroll
    for (int mi = 0; mi < 8; ++mi) {
        int row = m0 + wm * 128 + mi * 16 + fq * 4;
#pragma unroll
        for (int nj = 0; nj < 4; ++nj) {
            int col = n0 + wn * 64 + nj * 16 + fr;
            float bv = bs[col];
            f32x4 v = acc[mi][nj];
#pragma unroll
            for (int r = 0; r < 4; ++r)
                O[(size_t)(row + r) * ND + col] = v[r] + bv;
        }
    }
}

extern "C" void kernel_launch(void* const* d_in, const int* in_sizes, int n_in,
                              void* d_out, int out_size, void* d_ws, size_t ws_size,
                              hipStream_t stream) {
    const float* x      = (const float*)d_in[0];
    const float* scores = (const float*)d_in[1];
    const float* Wx     = (const float*)d_in[2];
    const float* eb     = (const float*)d_in[3];
    const int*   kp     = (const int*)d_in[4];
    float* out = (float*)d_out;
    char* ws = (char*)d_ws;

    float*    coef  = (float*)(ws);
    float*    bias  = (float*)(ws + 1024);
    ushort_t* xbuf  = (ushort_t*)(ws + 65536);
    ushort_t* wct   = (ushort_t*)(ws + 65536 + (size_t)NB * NS * ND * 2);
    float*    counts = out + (size_t)NB * NS * ND;

    routing_kernel<<<1, 64, 0, stream>>>(scores, kp, coef, counts);
    bias_kernel<<<dim3(ND / 256, NB), 256, 0, stream>>>(eb, coef, bias);
    combine_kernel<<<dim3(ND / 64, ND / 64, NB), 256, 0, stream>>>(Wx, coef, wct);
    convert_kernel<<<dim3(NB * NS * ND / 8 / 256), 256, 0, stream>>>(x, xbuf);
    gemm_kernel<<<256, 512, 0, stream>>>(xbuf, wct, bias, out);
}